// Round 1
// baseline (50099.683 us; speedup 1.0000x reference)
//
#include <hip/hip_runtime.h>

#define N_PTS 40000
#define C_IN 64
#define C_OUT 128
#define K_NN 16
#define M_SAMPLES 10001   // int(40000*0.25)+1

#define NGROUPS 625       // 40000 / 64, exact
#define NSG 63            // supergroups of 10 groups (last has 5)
#define GRID_DIM 8        // 8x8x8 buckets over [0,10)^3

// Exact reference arithmetic: (dx*dx + dy*dy) + dz*dz, no FMA contraction.
__device__ __forceinline__ float dist3_exact(float dx, float dy, float dz) {
#pragma clang fp contract(off)
  return (dx * dx + dy * dy) + dz * dz;
}

// Morton-interleaved cell id so consecutive cells (and hence consecutive
// 64-point groups and 10-group supergroups) are spatially compact cubes.
__device__ __forceinline__ int cell_of(float x, float y, float z) {
  int cx = min(GRID_DIM - 1, max(0, (int)(x * 0.8f)));
  int cy = min(GRID_DIM - 1, max(0, (int)(y * 0.8f)));
  int cz = min(GRID_DIM - 1, max(0, (int)(z * 0.8f)));
  return ((cx & 1) << 2) | ((cx & 2) << 4) | ((cx & 4) << 6)
       | ((cy & 1) << 1) | ((cy & 2) << 3) | ((cy & 4) << 5)
       | (cz & 1) | ((cz & 2) << 2) | ((cz & 4) << 4);
}

// ---------------- bucketing prologue ----------------
__global__ void hist_kernel(const float* __restrict__ xyz, int* __restrict__ hist) {
  int p = blockIdx.x * 256 + threadIdx.x;
  if (p < N_PTS) {
    int c = cell_of(xyz[3 * p], xyz[3 * p + 1], xyz[3 * p + 2]);
    atomicAdd(&hist[c], 1);
  }
}

__global__ __launch_bounds__(512) void scan_kernel(const int* __restrict__ hist,
                                                   int* __restrict__ cursor) {
  __shared__ int tmp[512];
  int t = threadIdx.x;
  tmp[t] = hist[t];
  __syncthreads();
  for (int off = 1; off < 512; off <<= 1) {
    int v = tmp[t];
    int u = (t >= off) ? tmp[t - off] : 0;
    __syncthreads();
    tmp[t] = v + u;
    __syncthreads();
  }
  cursor[t] = (t == 0) ? 0 : tmp[t - 1];
}

__global__ void scatter_kernel(const float* __restrict__ xyz, int* __restrict__ cursor,
                               float* __restrict__ gxyz, int* __restrict__ gidx) {
  int p = blockIdx.x * 256 + threadIdx.x;
  if (p < N_PTS) {
    float x = xyz[3 * p], y = xyz[3 * p + 1], z = xyz[3 * p + 2];
    int c = cell_of(x, y, z);
    int pos = atomicAdd(&cursor[c], 1);
    gxyz[3 * pos + 0] = x;
    gxyz[3 * pos + 1] = y;
    gxyz[3 * pos + 2] = z;
    gidx[pos] = p;
  }
}

__global__ __launch_bounds__(64) void bbox_kernel(const float* __restrict__ gxyz,
                                                  float* __restrict__ bbox) {
  int g = blockIdx.x, lane = threadIdx.x;
  int s = g * 64 + lane;
  float x = gxyz[3 * s], y = gxyz[3 * s + 1], z = gxyz[3 * s + 2];
  float lox = x, hix = x, loy = y, hiy = y, loz = z, hiz = z;
#pragma unroll
  for (int off = 32; off > 0; off >>= 1) {
    lox = fminf(lox, __shfl_xor(lox, off)); hix = fmaxf(hix, __shfl_xor(hix, off));
    loy = fminf(loy, __shfl_xor(loy, off)); hiy = fmaxf(hiy, __shfl_xor(hiy, off));
    loz = fminf(loz, __shfl_xor(loz, off)); hiz = fmaxf(hiz, __shfl_xor(hiz, off));
  }
  if (lane == 0) {
    bbox[g * 6 + 0] = lox; bbox[g * 6 + 1] = hix;
    bbox[g * 6 + 2] = loy; bbox[g * 6 + 3] = hiy;
    bbox[g * 6 + 4] = loz; bbox[g * 6 + 5] = hiz;
  }
}

// ---------------- in-wave reduction primitives ----------------
// xor1/xor2 via DPP quad_perm (cheap VALU); xor4/8/16 via ds_swizzle
// (verified BitMode patterns); xor32 via __shfl_xor (ds_bpermute).
__device__ __forceinline__ int lxor1(int x) {
  return __builtin_amdgcn_update_dpp(0, x, 0xB1, 0xF, 0xF, true);   // quad_perm [1,0,3,2]
}
__device__ __forceinline__ int lxor2(int x) {
  return __builtin_amdgcn_update_dpp(0, x, 0x4E, 0xF, 0xF, true);   // quad_perm [2,3,0,1]
}
__device__ __forceinline__ int lxor4(int x)  { return __builtin_amdgcn_ds_swizzle(x, 0x101F); }
__device__ __forceinline__ int lxor8(int x)  { return __builtin_amdgcn_ds_swizzle(x, 0x201F); }
__device__ __forceinline__ int lxor16(int x) { return __builtin_amdgcn_ds_swizzle(x, 0x401F); }

__device__ __forceinline__ float wmax_f(float v) {
  v = fmaxf(v, __int_as_float(lxor1(__float_as_int(v))));
  v = fmaxf(v, __int_as_float(lxor2(__float_as_int(v))));
  v = fmaxf(v, __int_as_float(lxor4(__float_as_int(v))));
  v = fmaxf(v, __int_as_float(lxor8(__float_as_int(v))));
  v = fmaxf(v, __int_as_float(lxor16(__float_as_int(v))));
  v = fmaxf(v, __shfl_xor(v, 32));
  return v;
}
__device__ __forceinline__ int wmin_i(int v) {
  v = min(v, lxor1(v)); v = min(v, lxor2(v)); v = min(v, lxor4(v));
  v = min(v, lxor8(v)); v = min(v, lxor16(v)); v = min(v, __shfl_xor(v, 32));
  return v;
}

// ---------------- single-wave pruned FPS: zero barriers ----------------
__global__ __launch_bounds__(64) void fps_kernel(
    const float* __restrict__ xyz, const float* __restrict__ gxyz,
    const int* __restrict__ gidx, const float* __restrict__ bbox,
    float* __restrict__ nxyz_out) {
  // LDS: 160000 + 2500 + 1250 = 163750 <= 163840
  __shared__ float dist_s[N_PTS];
  __shared__ float maxv_s[NGROUPS];
  __shared__ unsigned short glist_s[NGROUPS];

  const int lane = threadIdx.x;

  for (int i = lane; i < N_PTS; i += 64) dist_s[i] = 1e10f;
  for (int i = lane; i < NGROUPS; i += 64) maxv_s[i] = 1e10f;

  // supergroup bbox in registers: lane sg (<63) owns groups [sg*10, sg*10+10)
  float slox = 1e30f, shix = -1e30f, sloy = 1e30f, shiy = -1e30f;
  float sloz = 1e30f, shiz = -1e30f;
  if (lane < NSG) {
#pragma unroll
    for (int i = 0; i < 10; ++i) {
      int g = lane * 10 + i;
      if (g < NGROUPS) {
        slox = fminf(slox, bbox[g * 6 + 0]); shix = fmaxf(shix, bbox[g * 6 + 1]);
        sloy = fminf(sloy, bbox[g * 6 + 2]); shiy = fmaxf(shiy, bbox[g * 6 + 3]);
        sloz = fminf(sloz, bbox[g * 6 + 4]); shiz = fmaxf(shiz, bbox[g * 6 + 5]);
      }
    }
  }
  const int sgsel = lane / 10;            // 0..5 useful, 6 for lanes 60..63
  const int memb = lane - sgsel * 10;

  float lx = xyz[0], ly = xyz[1], lz = xyz[2];  // center 0 = point 0
  float V = 1e10f;                              // upper bound on all maxv

  __syncthreads();  // single wave; just pins the LDS init before use

  for (int s = 0;; ++s) {
    if (lane == 0) {
      nxyz_out[3 * s + 0] = lx;
      nxyz_out[3 * s + 1] = ly;
      nxyz_out[3 * s + 2] = lz;
    }
    if (s == M_SAMPLES - 1) break;

    // ---- A1: supergroup prune vs V (maxv[g] <= V, so lb_sg >= V => all skip) ----
    bool sga = false;
    if (lane < NSG) {
      float ex = fmaxf(fmaxf(slox - lx, lx - shix), 0.f);
      float ey = fmaxf(fmaxf(sloy - ly, ly - shiy), 0.f);
      float ez = fmaxf(fmaxf(sloz - lz, lz - shiz), 0.f);
      float lb = ex * ex + ey * ey + ez * ez;
      sga = (lb * 0.99999f < V);
    }
    unsigned long long sgmask = __ballot(sga);

    // ---- A2: test member groups of active supergroups, build glist ----
    int nga = 0;
    while (sgmask) {
      int b0 = __builtin_ctzll(sgmask); sgmask &= sgmask - 1;
      int b1 = -1, b2 = -1, b3 = -1, b4 = -1, b5 = -1;
      if (sgmask) { b1 = __builtin_ctzll(sgmask); sgmask &= sgmask - 1; }
      if (sgmask) { b2 = __builtin_ctzll(sgmask); sgmask &= sgmask - 1; }
      if (sgmask) { b3 = __builtin_ctzll(sgmask); sgmask &= sgmask - 1; }
      if (sgmask) { b4 = __builtin_ctzll(sgmask); sgmask &= sgmask - 1; }
      if (sgmask) { b5 = __builtin_ctzll(sgmask); sgmask &= sgmask - 1; }
      int mysg = (sgsel == 0) ? b0 : (sgsel == 1) ? b1 : (sgsel == 2) ? b2
               : (sgsel == 3) ? b3 : (sgsel == 4) ? b4 : (sgsel == 5) ? b5 : -1;
      bool ok = (mysg >= 0);
      int g = mysg * 10 + memb;
      ok = ok && (g < NGROUPS);
      bool act = false;
      if (ok) {
        const float2* bb = (const float2*)(bbox + g * 6);
        float2 bx = bb[0], by = bb[1], bz = bb[2];
        float ex = fmaxf(fmaxf(bx.x - lx, lx - bx.y), 0.f);
        float ey = fmaxf(fmaxf(by.x - ly, ly - by.y), 0.f);
        float ez = fmaxf(fmaxf(bz.x - lz, lz - bz.y), 0.f);
        float lb = ex * ex + ey * ey + ez * ez;
        act = (lb * 0.99999f < maxv_s[g]);  // skip only when provably no change
      }
      unsigned long long am = __ballot(act);
      if (act) {
        int rank = __popcll(am & ((1ull << lane) - 1ull));
        glist_s[nga + rank] = (unsigned short)g;
      }
      nga += __popcll(am);
    }

    // ---- B: update active groups, batched 4 (pipelines memory latency) ----
    for (int j0 = 0; j0 < nga; j0 += 4) {
      const int bc = min(4, nga - j0);
      int gg[4];
      float px[4], py[4], pz[4], od[4];
#pragma unroll
      for (int u = 0; u < 4; ++u) {
        // duplicate group j0 for inactive slots: idempotent (same nd/mv rewrite)
        gg[u] = (int)glist_s[(u < bc) ? (j0 + u) : j0];
        int slot = gg[u] * 64 + lane;
        px[u] = gxyz[3 * slot + 0];
        py[u] = gxyz[3 * slot + 1];
        pz[u] = gxyz[3 * slot + 2];
        od[u] = dist_s[slot];
      }
#pragma unroll
      for (int u = 0; u < 4; ++u) {
        float dx, dy, dz;
        {
#pragma clang fp contract(off)
          dx = px[u] - lx; dy = py[u] - ly; dz = pz[u] - lz;
        }
        float d = dist3_exact(dx, dy, dz);
        float nd = fminf(od[u], d);
        int slot = gg[u] * 64 + lane;
        dist_s[slot] = nd;
        float mv = wmax_f(nd);
        if (lane == 0) maxv_s[gg[u]] = mv;
      }
    }

    // ---- C1: V = max over group maxima; candidate group; exact tie detect ----
    float m10[10];
#pragma unroll
    for (int i = 0; i < 10; ++i) {
      int g = i * 64 + lane;
      m10[i] = (g < NGROUPS) ? maxv_s[g] : -1.f;
    }
    float vb = m10[0];
    int gb = lane;
#pragma unroll
    for (int i = 1; i < 10; ++i) {
      if (m10[i] > vb) { vb = m10[i]; gb = i * 64 + lane; }
    }
    {
      float ov; int og;
#define ASTEP(SHV, SHG)                                        \
      ov = (SHV); og = (SHG);                                  \
      if (ov > vb || (ov == vb && og < gb)) { vb = ov; gb = og; }
      ASTEP(__int_as_float(lxor1(__float_as_int(vb))), lxor1(gb));
      ASTEP(__int_as_float(lxor2(__float_as_int(vb))), lxor2(gb));
      ASTEP(__int_as_float(lxor4(__float_as_int(vb))), lxor4(gb));
      ASTEP(__int_as_float(lxor8(__float_as_int(vb))), lxor8(gb));
      ASTEP(__int_as_float(lxor16(__float_as_int(vb))), lxor16(gb));
      ASTEP(__shfl_xor(vb, 32), __shfl_xor(gb, 32));
#undef ASTEP
    }
    V = vb;
    const int gbest = gb;
    int lc = 0;
#pragma unroll
    for (int i = 0; i < 10; ++i) lc += (m10[i] == V) ? 1 : 0;
    unsigned long long t1 = __ballot(lc != 0);
    bool multi = (__popcll(t1) > 1) || (__ballot(lc > 1) != 0ull);

    // ---- C3: exact argmax (min original index among dist==V) ----
    if (!multi) {
      int slot = gbest * 64 + lane;
      float dd = dist_s[slot];
      int gi = gidx[slot];
      float qx = gxyz[3 * slot + 0];   // speculative: winner coords via shuffle
      float qy = gxyz[3 * slot + 1];
      float qz = gxyz[3 * slot + 2];
      int enc = (dd == V) ? ((gi << 6) | lane) : 0x7fffffff;
      enc = wmin_i(enc);
      int wl = enc & 63;
      lx = __shfl(qx, wl); ly = __shfl(qy, wl); lz = __shfl(qz, wl);
    } else {
      // rare exact path: multiple groups tied at V
      int best = 0x7fffffff;
      int bg = -1;
#pragma unroll 1
      for (int i = 0; i < 10; ++i) {
        unsigned long long m = __ballot(m10[i] == V);
        while (m) {
          int l = __builtin_ctzll(m); m &= m - 1;
          int g = i * 64 + l;
          int slot = g * 64 + lane;
          float dd = dist_s[slot];
          int enc2 = (dd == V) ? ((gidx[slot] << 6) | lane) : 0x7fffffff;
          enc2 = wmin_i(enc2);
          if (enc2 < best) { best = enc2; bg = g; }
        }
      }
      int slot = bg * 64 + (best & 63);
      lx = gxyz[3 * slot + 0]; ly = gxyz[3 * slot + 1]; lz = gxyz[3 * slot + 2];
    }
  }
}

// ---------------- KNN: one wave per center ----------------
#define KNN_TILE 2048

__device__ __forceinline__ float knn_dist_exact(float sn, float cx, float cy,
                                                float cz, float x, float y,
                                                float z) {
#pragma clang fp contract(off)
  float sx = (x * x + y * y) + z * z;
  float dot = (cx * x + cy * y) + cz * z;
  return (sn - 2.0f * dot) + sx;
}

__global__ __launch_bounds__(256) void knn_kernel(
    const float* __restrict__ xyz, const float* __restrict__ nxyz,
    int* __restrict__ knn_out) {
  __shared__ float txyz[KNN_TILE * 3];
  const int lane = threadIdx.x & 63;
  const int wv = threadIdx.x >> 6;
  const int m = blockIdx.x * 4 + wv;
  const bool active = (m < M_SAMPLES);

  float cx = 0.f, cy = 0.f, cz = 0.f;
  if (active) {
    cx = nxyz[3 * m + 0]; cy = nxyz[3 * m + 1]; cz = nxyz[3 * m + 2];
  }
  float sn;
  {
#pragma clang fp contract(off)
    sn = (cx * cx + cy * cy) + cz * cz;
  }

  float hd[K_NN];
  int hi[K_NN];
#pragma unroll
  for (int i = 0; i < K_NN; ++i) { hd[i] = 3.4e38f; hi[i] = 0x7fffffff; }

  for (int base = 0; base < N_PTS; base += KNN_TILE) {
    const int cnt = min(KNN_TILE, N_PTS - base);
    __syncthreads();
    {
      const float4* src4 = (const float4*)(xyz + (size_t)base * 3);
      float4* dst4 = (float4*)txyz;
      const int n4 = (cnt * 3) >> 2;
      for (int i = threadIdx.x; i < n4; i += 256) dst4[i] = src4[i];
    }
    __syncthreads();
    for (int p = lane; p < cnt; p += 64) {
      float x = txyz[3 * p + 0], y = txyz[3 * p + 1], z = txyz[3 * p + 2];
      float d = knn_dist_exact(sn, cx, cy, cz, x, y, z);
      int gi = base + p;
      if (d < hd[K_NN - 1] || (d == hd[K_NN - 1] && gi < hi[K_NN - 1])) {
        hd[K_NN - 1] = d;
        hi[K_NN - 1] = gi;
#pragma unroll
        for (int i = K_NN - 1; i > 0; --i) {
          bool sw = (hd[i] < hd[i - 1]) ||
                    (hd[i] == hd[i - 1] && hi[i] < hi[i - 1]);
          if (sw) {
            float td = hd[i]; hd[i] = hd[i - 1]; hd[i - 1] = td;
            int ti = hi[i]; hi[i] = hi[i - 1]; hi[i - 1] = ti;
          }
        }
      }
    }
  }

  int keep = 0;
#pragma unroll 1
  for (int r = 0; r < K_NN; ++r) {
    float d0 = hd[0];
    int i0 = hi[0];
    int l0 = lane;
#pragma unroll
    for (int off = 32; off > 0; off >>= 1) {
      float od = __shfl_xor(d0, off);
      int oi = __shfl_xor(i0, off);
      int ol = __shfl_xor(l0, off);
      if (od < d0 || (od == d0 && oi < i0)) { d0 = od; i0 = oi; l0 = ol; }
    }
    if (lane == r) keep = i0;
    if (lane == l0) {
#pragma unroll
      for (int i = 0; i < K_NN - 1; ++i) { hd[i] = hd[i + 1]; hi[i] = hi[i + 1]; }
      hd[K_NN - 1] = 3.4e38f;
      hi[K_NN - 1] = 0x7fffffff;
    }
  }
  if (active && lane < K_NN) knn_out[m * K_NN + lane] = keep;
}

// -------- gather + LayerNorm + Linear + maxpool: one block per center --------
__global__ __launch_bounds__(128) void head_kernel(
    const float* __restrict__ feats, const int* __restrict__ knn,
    const float* __restrict__ lnw, const float* __restrict__ lnb,
    const float* __restrict__ W, float* __restrict__ out,
    float* __restrict__ noff) {
  const int m = blockIdx.x;
  const int t = threadIdx.x;
  __shared__ float g[K_NN][68];
  __shared__ float mu_s[K_NN], rs_s[K_NN];

  for (int q = t; q < 256; q += 128) {
    int k = q >> 4, c4 = q & 15;
    int src = knn[m * K_NN + k];
    float4 v = ((const float4*)(feats + (size_t)src * C_IN))[c4];
    g[k][c4 * 4 + 0] = v.x;
    g[k][c4 * 4 + 1] = v.y;
    g[k][c4 * 4 + 2] = v.z;
    g[k][c4 * 4 + 3] = v.w;
  }
  __syncthreads();
  if (t < K_NN) {
    float s = 0.f;
    for (int c = 0; c < C_IN; ++c) s += g[t][c];
    float mu = s * (1.0f / 64.0f);
    float v = 0.f;
    for (int c = 0; c < C_IN; ++c) {
      float d = g[t][c] - mu;
      v += d * d;
    }
    v *= (1.0f / 64.0f);
    mu_s[t] = mu;
    rs_s[t] = rsqrtf(v + 1e-5f);
  }
  __syncthreads();
  for (int q = t; q < K_NN * C_IN; q += 128) {
    int k = q >> 6, c = q & 63;
    g[k][c] = (g[k][c] - mu_s[k]) * rs_s[k] * lnw[c] + lnb[c];
  }
  __syncthreads();
  float acc[K_NN];
#pragma unroll
  for (int k = 0; k < K_NN; ++k) acc[k] = 0.f;
  for (int c = 0; c < C_IN; ++c) {
    float w = W[c * C_OUT + t];
#pragma unroll
    for (int k = 0; k < K_NN; ++k) acc[k] = fmaf(g[k][c], w, acc[k]);
  }
  float mx = acc[0];
#pragma unroll
  for (int k = 1; k < K_NN; ++k) mx = fmaxf(mx, acc[k]);
  out[(size_t)m * C_OUT + t] = mx;

  if (m == 0 && t == 0) noff[0] = (float)M_SAMPLES;
}

extern "C" void kernel_launch(void* const* d_in, const int* in_sizes, int n_in,
                              void* d_out, int out_size, void* d_ws,
                              size_t ws_size, hipStream_t stream) {
  const float* feats = (const float*)d_in[0];
  const float* xyz = (const float*)d_in[1];
  const float* lnw = (const float*)d_in[3];
  const float* lnb = (const float*)d_in[4];
  const float* W = (const float*)d_in[5];

  float* out = (float*)d_out;
  float* nxyz = out + (size_t)M_SAMPLES * C_OUT;
  float* noff = nxyz + (size_t)M_SAMPLES * 3;

  char* ws = (char*)d_ws;
  int* hist = (int*)(ws + 0);              // 512 ints
  int* cursor = (int*)(ws + 2048);         // 512 ints
  float* gxyz = (float*)(ws + 4096);       // 40000*3 f = 480000 B
  int* gidx = (int*)(ws + 484096);         // 40000 i  = 160000 B
  float* bbox = (float*)(ws + 644096);     // 625*6 f  = 15000 B
  int* knn = (int*)(ws + 659104);          // 10001*16 i

  hipMemsetAsync(hist, 0, 512 * sizeof(int), stream);
  hist_kernel<<<(N_PTS + 255) / 256, 256, 0, stream>>>(xyz, hist);
  scan_kernel<<<1, 512, 0, stream>>>(hist, cursor);
  scatter_kernel<<<(N_PTS + 255) / 256, 256, 0, stream>>>(xyz, cursor, gxyz, gidx);
  bbox_kernel<<<NGROUPS, 64, 0, stream>>>(gxyz, bbox);
  fps_kernel<<<1, 64, 0, stream>>>(xyz, gxyz, gidx, bbox, nxyz);
  knn_kernel<<<(M_SAMPLES + 3) / 4, 256, 0, stream>>>(xyz, nxyz, knn);
  head_kernel<<<M_SAMPLES, 128, 0, stream>>>(feats, knn, lnw, lnb, W, out, noff);
}

// Round 2
// 20279.164 us; speedup vs baseline: 2.4705x; 2.4705x over previous
//
#include <hip/hip_runtime.h>

#define N_PTS 40000
#define C_IN 64
#define C_OUT 128
#define K_NN 16
#define M_SAMPLES 10001   // int(40000*0.25)+1

#define NGROUPS 625       // 40000 / 64, exact
#define GRID_DIM 8        // 8x8x8 buckets over [0,10)^3

// Exact reference arithmetic: (dx*dx + dy*dy) + dz*dz, no FMA contraction.
__device__ __forceinline__ float dist3_exact(float dx, float dy, float dz) {
#pragma clang fp contract(off)
  return (dx * dx + dy * dy) + dz * dz;
}

// Morton-interleaved cell id: consecutive cells are spatially compact, so
// consecutive 64-point groups get tight bboxes.
__device__ __forceinline__ int cell_of(float x, float y, float z) {
  int cx = min(GRID_DIM - 1, max(0, (int)(x * 0.8f)));
  int cy = min(GRID_DIM - 1, max(0, (int)(y * 0.8f)));
  int cz = min(GRID_DIM - 1, max(0, (int)(z * 0.8f)));
  return ((cx & 1) << 2) | ((cx & 2) << 4) | ((cx & 4) << 6)
       | ((cy & 1) << 1) | ((cy & 2) << 3) | ((cy & 4) << 5)
       | (cz & 1) | ((cz & 2) << 2) | ((cz & 4) << 4);
}

// ---------------- bucketing prologue ----------------
__global__ void hist_kernel(const float* __restrict__ xyz, int* __restrict__ hist) {
  int p = blockIdx.x * 256 + threadIdx.x;
  if (p < N_PTS) {
    int c = cell_of(xyz[3 * p], xyz[3 * p + 1], xyz[3 * p + 2]);
    atomicAdd(&hist[c], 1);
  }
}

__global__ __launch_bounds__(512) void scan_kernel(const int* __restrict__ hist,
                                                   int* __restrict__ cursor) {
  __shared__ int tmp[512];
  int t = threadIdx.x;
  tmp[t] = hist[t];
  __syncthreads();
  for (int off = 1; off < 512; off <<= 1) {
    int v = tmp[t];
    int u = (t >= off) ? tmp[t - off] : 0;
    __syncthreads();
    tmp[t] = v + u;
    __syncthreads();
  }
  cursor[t] = (t == 0) ? 0 : tmp[t - 1];
}

__global__ void scatter_kernel(const float* __restrict__ xyz, int* __restrict__ cursor,
                               float* __restrict__ gxyz, int* __restrict__ gidx) {
  int p = blockIdx.x * 256 + threadIdx.x;
  if (p < N_PTS) {
    float x = xyz[3 * p], y = xyz[3 * p + 1], z = xyz[3 * p + 2];
    int c = cell_of(x, y, z);
    int pos = atomicAdd(&cursor[c], 1);
    gxyz[3 * pos + 0] = x;
    gxyz[3 * pos + 1] = y;
    gxyz[3 * pos + 2] = z;
    gidx[pos] = p;
  }
}

__global__ __launch_bounds__(64) void bbox_kernel(const float* __restrict__ gxyz,
                                                  float* __restrict__ bbox) {
  int g = blockIdx.x, lane = threadIdx.x;
  int s = g * 64 + lane;
  float x = gxyz[3 * s], y = gxyz[3 * s + 1], z = gxyz[3 * s + 2];
  float lox = x, hix = x, loy = y, hiy = y, loz = z, hiz = z;
#pragma unroll
  for (int off = 32; off > 0; off >>= 1) {
    lox = fminf(lox, __shfl_xor(lox, off)); hix = fmaxf(hix, __shfl_xor(hix, off));
    loy = fminf(loy, __shfl_xor(loy, off)); hiy = fmaxf(hiy, __shfl_xor(hiy, off));
    loz = fminf(loz, __shfl_xor(loz, off)); hiz = fmaxf(hiz, __shfl_xor(hiz, off));
  }
  if (lane == 0) {
    bbox[g * 6 + 0] = lox; bbox[g * 6 + 1] = hix;
    bbox[g * 6 + 2] = loy; bbox[g * 6 + 3] = hiy;
    bbox[g * 6 + 4] = loz; bbox[g * 6 + 5] = hiz;
  }
}

// ---------------- DPP wave reductions: pure VALU, ~8 cyc per step ----------------
// row_shr:1/2/4/8 then row_bcast15/31; result valid in lane 63.
// old=0 + bound_ctrl=true => invalid lanes contribute 0 under either LLVM
// bound_ctrl semantic. All reduced values are kept >= 0 so 0 is an identity.
template <int CTRL>
__device__ __forceinline__ float dpp_maxf(float v) {
  int s = __builtin_amdgcn_update_dpp(0, __float_as_int(v), CTRL, 0xF, 0xF, true);
  return fmaxf(v, __int_as_float(s));
}
// lane 63 holds the wave max; other lanes partial. v must be >= 0.
__device__ __forceinline__ float wave_max_f_l63(float v) {
  v = dpp_maxf<0x111>(v); v = dpp_maxf<0x112>(v); v = dpp_maxf<0x114>(v);
  v = dpp_maxf<0x118>(v); v = dpp_maxf<0x142>(v); v = dpp_maxf<0x143>(v);
  return v;
}
__device__ __forceinline__ float wave_max_f_bcast(float v) {
  v = wave_max_f_l63(v);
  return __int_as_float(__builtin_amdgcn_readlane(__float_as_int(v), 63));
}
template <int CTRL>
__device__ __forceinline__ int dpp_maxi(int v) {
  int s = __builtin_amdgcn_update_dpp(0, v, CTRL, 0xF, 0xF, true);
  return max(v, s);
}
// wave max of a value >= 0, broadcast to all lanes via readlane (SGPR).
__device__ __forceinline__ int wave_max_i0(int v) {
  v = dpp_maxi<0x111>(v); v = dpp_maxi<0x112>(v); v = dpp_maxi<0x114>(v);
  v = dpp_maxi<0x118>(v); v = dpp_maxi<0x142>(v); v = dpp_maxi<0x143>(v);
  return __builtin_amdgcn_readlane(v, 63);
}

// ---------------- pruned FPS: 1024 threads, 2 barriers / iteration ----------------
__global__ __launch_bounds__(1024) void fps_kernel(
    const float* __restrict__ xyz, const float* __restrict__ gxyz,
    const int* __restrict__ gidx, const float* __restrict__ bbox,
    float* __restrict__ nxyz_out) {
  // LDS: 160000 + 2500 + 1250 + 8 (+pad) = 163760 <= 163840
  __shared__ float dist_s[N_PTS];
  __shared__ float maxv_s[NGROUPS];
  __shared__ unsigned short list_s[NGROUPS];
  __shared__ int cnt_a[2];

  const int t = threadIdx.x;
  const int lane = t & 63;
  const int wv = t >> 6;  // 0..15

  for (int i = t; i < N_PTS; i += 1024) dist_s[i] = 1e10f;
  for (int i = t; i < NGROUPS; i += 1024) maxv_s[i] = 1e10f;
  if (t == 0) { cnt_a[0] = 0; cnt_a[1] = 0; }

  // cache my group's bbox in registers (thread t owns group t, t<625)
  float blox = 0.f, bhix = 0.f, bloy = 0.f, bhiy = 0.f, bloz = 0.f, bhiz = 0.f;
  if (t < NGROUPS) {
    blox = bbox[t * 6 + 0]; bhix = bbox[t * 6 + 1];
    bloy = bbox[t * 6 + 2]; bhiy = bbox[t * 6 + 3];
    bloz = bbox[t * 6 + 4]; bhiz = bbox[t * 6 + 5];
  }

  float lx = xyz[0], ly = xyz[1], lz = xyz[2];  // center 0 = point 0
  __syncthreads();

  for (int s = 0;; ++s) {
    if (t == 0) {
      nxyz_out[3 * s + 0] = lx;
      nxyz_out[3 * s + 1] = ly;
      nxyz_out[3 * s + 2] = lz;
    }
    if (s == M_SAMPLES - 1) break;
    const int par = s & 1;

    // ---- A: conservative group skip test; build active list ----
    bool active = false;
    if (t < NGROUPS) {
      float ex = fmaxf(fmaxf(blox - lx, lx - bhix), 0.f);
      float ey = fmaxf(fmaxf(bloy - ly, ly - bhiy), 0.f);
      float ez = fmaxf(fmaxf(bloz - lz, lz - bhiz), 0.f);
      float lb = ex * ex + ey * ey + ez * ez;
      active = (lb * 0.99999f < maxv_s[t]);  // skip only when provably no change
    }
    unsigned long long mask = __ballot(active);
    int base = 0;
    if (lane == 0 && mask) base = atomicAdd(&cnt_a[par], __popcll(mask));
    base = __builtin_amdgcn_readfirstlane(base);
    if (active) {
      int rank = __popcll(mask & ((1ull << lane) - 1ull));
      list_s[base + rank] = (unsigned short)t;
    }
    __syncthreads();  // barrier 1: active list complete
    const int na = cnt_a[par];
    if (t == 0) cnt_a[1 - par] = 0;  // next iter's slot; next atomics are after bar 2

    // ---- B: update active groups (one wave per group, 1 point per lane) ----
    for (int i = wv; i < na; i += 16) {
      int g = list_s[i];
      int slot = g * 64 + lane;
      float x = gxyz[3 * slot + 0], y = gxyz[3 * slot + 1], z = gxyz[3 * slot + 2];
      float od = dist_s[slot];
      float dx, dy, dz;
      {
#pragma clang fp contract(off)
        dx = x - lx; dy = y - ly; dz = z - lz;
      }
      float d = dist3_exact(dx, dy, dz);
      float nd = fminf(od, d);
      dist_s[slot] = nd;
      float mv = wave_max_f_l63(nd);      // nd >= 0
      if (lane == 63) maxv_s[g] = mv;
    }
    __syncthreads();  // barrier 2: dist/maxv updates visible

    // ---- C: every wave redundantly finds the global argmax (no more barriers) ----
    float m10[10];
#pragma unroll
    for (int i = 0; i < 10; ++i) {
      int g = i * 64 + lane;
      m10[i] = (g < NGROUPS) ? maxv_s[g] : -1.f;
    }
    float vb = m10[0];
#pragma unroll
    for (int i = 1; i < 10; ++i) vb = fmaxf(vb, m10[i]);
    const float V = wave_max_f_bcast(vb);  // vb >= 0 for every lane (g<625 exists)

    unsigned long long mk[10];
    int tot = 0;
#pragma unroll
    for (int i = 0; i < 10; ++i) {
      mk[i] = __ballot(m10[i] == V);
      tot += __popcll(mk[i]);
    }

    if (tot == 1) {
      // unique group achieving V (the common case)
      int i0 = 0;
#pragma unroll
      for (int i = 9; i >= 0; --i)
        if (mk[i]) i0 = i;
      const int gbest = i0 * 64 + __builtin_ctzll(mk[i0]);
      int slot = gbest * 64 + lane;
      float dd = dist_s[slot];
      int gi = gidx[slot];                 // speculative, off critical path
      float qx = gxyz[3 * slot + 0];
      float qy = gxyz[3 * slot + 1];
      float qz = gxyz[3 * slot + 2];
      // exact argmax tie-break: min original index among dist==V
      int enc = (dd == V) ? ((gi << 6) | lane) : 0x7fffffff;
      int mx = wave_max_i0(0x7fffffff - enc);   // >= 0; min via complement
      int wl = (0x7fffffff - mx) & 63;          // uniform winner lane
      lx = __int_as_float(__builtin_amdgcn_readlane(__float_as_int(qx), wl));
      ly = __int_as_float(__builtin_amdgcn_readlane(__float_as_int(qy), wl));
      lz = __int_as_float(__builtin_amdgcn_readlane(__float_as_int(qz), wl));
    } else {
      // rare exact path: multiple (group,lane) slots tied at V
      int best = 0x7fffffff;
      int bg = 0;
#pragma unroll 1
      for (int i = 0; i < 10; ++i) {
        unsigned long long m = mk[i];
        while (m) {
          int l = __builtin_ctzll(m); m &= m - 1;
          int g = i * 64 + l;
          int slot = g * 64 + lane;
          float dd = dist_s[slot];
          int enc = (dd == V) ? ((gidx[slot] << 6) | lane) : 0x7fffffff;
          int e = 0x7fffffff - wave_max_i0(0x7fffffff - enc);
          if (e < best) { best = e; bg = g; }
        }
      }
      int slot = bg * 64 + (best & 63);
      lx = gxyz[3 * slot + 0]; ly = gxyz[3 * slot + 1]; lz = gxyz[3 * slot + 2];
    }
  }
}

// ---------------- KNN: one wave per center ----------------
#define KNN_TILE 2048

__device__ __forceinline__ float knn_dist_exact(float sn, float cx, float cy,
                                                float cz, float x, float y,
                                                float z) {
#pragma clang fp contract(off)
  float sx = (x * x + y * y) + z * z;
  float dot = (cx * x + cy * y) + cz * z;
  return (sn - 2.0f * dot) + sx;
}

__global__ __launch_bounds__(256) void knn_kernel(
    const float* __restrict__ xyz, const float* __restrict__ nxyz,
    int* __restrict__ knn_out) {
  __shared__ float txyz[KNN_TILE * 3];
  const int lane = threadIdx.x & 63;
  const int wv = threadIdx.x >> 6;
  const int m = blockIdx.x * 4 + wv;
  const bool active = (m < M_SAMPLES);

  float cx = 0.f, cy = 0.f, cz = 0.f;
  if (active) {
    cx = nxyz[3 * m + 0]; cy = nxyz[3 * m + 1]; cz = nxyz[3 * m + 2];
  }
  float sn;
  {
#pragma clang fp contract(off)
    sn = (cx * cx + cy * cy) + cz * cz;
  }

  float hd[K_NN];
  int hi[K_NN];
#pragma unroll
  for (int i = 0; i < K_NN; ++i) { hd[i] = 3.4e38f; hi[i] = 0x7fffffff; }

  for (int base = 0; base < N_PTS; base += KNN_TILE) {
    const int cnt = min(KNN_TILE, N_PTS - base);
    __syncthreads();
    {
      const float4* src4 = (const float4*)(xyz + (size_t)base * 3);
      float4* dst4 = (float4*)txyz;
      const int n4 = (cnt * 3) >> 2;
      for (int i = threadIdx.x; i < n4; i += 256) dst4[i] = src4[i];
    }
    __syncthreads();
    for (int p = lane; p < cnt; p += 64) {
      float x = txyz[3 * p + 0], y = txyz[3 * p + 1], z = txyz[3 * p + 2];
      float d = knn_dist_exact(sn, cx, cy, cz, x, y, z);
      int gi = base + p;
      if (d < hd[K_NN - 1] || (d == hd[K_NN - 1] && gi < hi[K_NN - 1])) {
        hd[K_NN - 1] = d;
        hi[K_NN - 1] = gi;
#pragma unroll
        for (int i = K_NN - 1; i > 0; --i) {
          bool sw = (hd[i] < hd[i - 1]) ||
                    (hd[i] == hd[i - 1] && hi[i] < hi[i - 1]);
          if (sw) {
            float td = hd[i]; hd[i] = hd[i - 1]; hd[i - 1] = td;
            int ti = hi[i]; hi[i] = hi[i - 1]; hi[i - 1] = ti;
          }
        }
      }
    }
  }

  int keep = 0;
#pragma unroll 1
  for (int r = 0; r < K_NN; ++r) {
    float d0 = hd[0];
    int i0 = hi[0];
    int l0 = lane;
#pragma unroll
    for (int off = 32; off > 0; off >>= 1) {
      float od = __shfl_xor(d0, off);
      int oi = __shfl_xor(i0, off);
      int ol = __shfl_xor(l0, off);
      if (od < d0 || (od == d0 && oi < i0)) { d0 = od; i0 = oi; l0 = ol; }
    }
    if (lane == r) keep = i0;
    if (lane == l0) {
#pragma unroll
      for (int i = 0; i < K_NN - 1; ++i) { hd[i] = hd[i + 1]; hi[i] = hi[i + 1]; }
      hd[K_NN - 1] = 3.4e38f;
      hi[K_NN - 1] = 0x7fffffff;
    }
  }
  if (active && lane < K_NN) knn_out[m * K_NN + lane] = keep;
}

// -------- gather + LayerNorm + Linear + maxpool: one block per center --------
__global__ __launch_bounds__(128) void head_kernel(
    const float* __restrict__ feats, const int* __restrict__ knn,
    const float* __restrict__ lnw, const float* __restrict__ lnb,
    const float* __restrict__ W, float* __restrict__ out,
    float* __restrict__ noff) {
  const int m = blockIdx.x;
  const int t = threadIdx.x;
  __shared__ float g[K_NN][68];
  __shared__ float mu_s[K_NN], rs_s[K_NN];

  for (int q = t; q < 256; q += 128) {
    int k = q >> 4, c4 = q & 15;
    int src = knn[m * K_NN + k];
    float4 v = ((const float4*)(feats + (size_t)src * C_IN))[c4];
    g[k][c4 * 4 + 0] = v.x;
    g[k][c4 * 4 + 1] = v.y;
    g[k][c4 * 4 + 2] = v.z;
    g[k][c4 * 4 + 3] = v.w;
  }
  __syncthreads();
  if (t < K_NN) {
    float s = 0.f;
    for (int c = 0; c < C_IN; ++c) s += g[t][c];
    float mu = s * (1.0f / 64.0f);
    float v = 0.f;
    for (int c = 0; c < C_IN; ++c) {
      float d = g[t][c] - mu;
      v += d * d;
    }
    v *= (1.0f / 64.0f);
    mu_s[t] = mu;
    rs_s[t] = rsqrtf(v + 1e-5f);
  }
  __syncthreads();
  for (int q = t; q < K_NN * C_IN; q += 128) {
    int k = q >> 6, c = q & 63;
    g[k][c] = (g[k][c] - mu_s[k]) * rs_s[k] * lnw[c] + lnb[c];
  }
  __syncthreads();
  float acc[K_NN];
#pragma unroll
  for (int k = 0; k < K_NN; ++k) acc[k] = 0.f;
  for (int c = 0; c < C_IN; ++c) {
    float w = W[c * C_OUT + t];
#pragma unroll
    for (int k = 0; k < K_NN; ++k) acc[k] = fmaf(g[k][c], w, acc[k]);
  }
  float mx = acc[0];
#pragma unroll
  for (int k = 1; k < K_NN; ++k) mx = fmaxf(mx, acc[k]);
  out[(size_t)m * C_OUT + t] = mx;

  if (m == 0 && t == 0) noff[0] = (float)M_SAMPLES;
}

extern "C" void kernel_launch(void* const* d_in, const int* in_sizes, int n_in,
                              void* d_out, int out_size, void* d_ws,
                              size_t ws_size, hipStream_t stream) {
  const float* feats = (const float*)d_in[0];
  const float* xyz = (const float*)d_in[1];
  const float* lnw = (const float*)d_in[3];
  const float* lnb = (const float*)d_in[4];
  const float* W = (const float*)d_in[5];

  float* out = (float*)d_out;
  float* nxyz = out + (size_t)M_SAMPLES * C_OUT;
  float* noff = nxyz + (size_t)M_SAMPLES * 3;

  char* ws = (char*)d_ws;
  int* hist = (int*)(ws + 0);              // 512 ints
  int* cursor = (int*)(ws + 2048);         // 512 ints
  float* gxyz = (float*)(ws + 4096);       // 40000*3 f = 480000 B
  int* gidx = (int*)(ws + 484096);         // 40000 i  = 160000 B
  float* bbox = (float*)(ws + 644096);     // 625*6 f  = 15000 B
  int* knn = (int*)(ws + 659104);          // 10001*16 i

  hipMemsetAsync(hist, 0, 512 * sizeof(int), stream);
  hist_kernel<<<(N_PTS + 255) / 256, 256, 0, stream>>>(xyz, hist);
  scan_kernel<<<1, 512, 0, stream>>>(hist, cursor);
  scatter_kernel<<<(N_PTS + 255) / 256, 256, 0, stream>>>(xyz, cursor, gxyz, gidx);
  bbox_kernel<<<NGROUPS, 64, 0, stream>>>(gxyz, bbox);
  fps_kernel<<<1, 1024, 0, stream>>>(xyz, gxyz, gidx, bbox, nxyz);
  knn_kernel<<<(M_SAMPLES + 3) / 4, 256, 0, stream>>>(xyz, nxyz, knn);
  head_kernel<<<M_SAMPLES, 128, 0, stream>>>(feats, knn, lnw, lnb, W, out, noff);
}